// Round 8
// baseline (779.428 us; speedup 1.0000x reference)
//
#include <hip/hip_runtime.h>
#include <hip/hip_bf16.h>
#include <string.h>

#define N_FEAT 128
#define HIDDEN 64
#define N_CLS  40
#define FILL_BLOCKS 1024
#define AGG_BLOCKS 1024
#define CHUNK_EDGES 16384        // big chunks -> one cursor atomic per bucket per chunk
#define STAGE_CAP 6144           // LDS staging capacity (expected ~2048 owned/chunk)
#define B_BITS 6                 // 64 dsts per bucket
#define SRC_BITS 17              // N <= 131072

typedef __bf16 bf16x8 __attribute__((ext_vector_type(8)));
typedef float  f32x4  __attribute__((ext_vector_type(4)));

union Frag { unsigned u[4]; bf16x8 v; };

// physical XCD id of the CU running this wave [measured: learn_hip m09]
static __device__ inline int get_xcc() {
    return (int)(__builtin_amdgcn_s_getreg((3 << 11) | 20) & 7u);
}

// ---------------- bf16 pack/unpack (manual, RNE) ----------------

static __device__ inline unsigned pack_bf16(float a, float b) {
    unsigned ba = __float_as_uint(a);
    unsigned bb = __float_as_uint(b);
    unsigned ra = (ba + 0x7fffu + ((ba >> 16) & 1u)) >> 16;
    unsigned rb = (bb + 0x7fffu + ((bb >> 16) & 1u)) >> 16;
    return (ra & 0xffffu) | (rb << 16);
}

static __device__ inline float2 unpack_bf16(unsigned v) {
    return make_float2(__uint_as_float(v << 16), __uint_as_float(v & 0xffff0000u));
}

// ---------------- edge layout detection ----------------

__global__ void detect_layout_kernel(const int* __restrict__ ei, int* __restrict__ flag) {
    int lane = threadIdx.x;                 // one wave
    int v = ei[2 * lane + 1];
    unsigned long long b = __ballot(v != 0);
    if (lane == 0) flag[0] = (b == 0ull) ? 1 : 0;   // 1 => int64 layout
}

// ---------------- bucket histogram: LDS hist per block, one flush ----------------

__global__ __launch_bounds__(256) void bucket_hist_kernel(const int* __restrict__ ei,
                                                          const int* __restrict__ flag,
                                                          unsigned* __restrict__ bcnt,
                                                          int E, int nbuk) {
    __shared__ unsigned h[2048];
    for (int i = threadIdx.x; i < nbuk; i += 256) h[i] = 0u;
    __syncthreads();
    bool is64 = (flag[0] != 0);
    if (is64) {
        int idx = blockIdx.x * 256 + threadIdx.x;
        int stride2 = gridDim.x * 256 * 2;
        int Eeven = E & ~1;
        for (int e = idx * 2; e < Eeven; e += stride2) {
            uint4 dv = *(const uint4*)(ei + (size_t)2 * E + (size_t)2 * e);
            atomicAdd(&h[((int)dv.x) >> B_BITS], 1u);
            atomicAdd(&h[((int)dv.z) >> B_BITS], 1u);
        }
        for (int e = Eeven + idx; e < E; e += gridDim.x * 256) {
            int d = ei[(size_t)2 * E + (size_t)2 * e];
            atomicAdd(&h[d >> B_BITS], 1u);
        }
    } else {
        const int* dstp = ei + E;
        for (int e = blockIdx.x * 256 + threadIdx.x; e < E; e += gridDim.x * 256) {
            int d = dstp[e];
            atomicAdd(&h[d >> B_BITS], 1u);
        }
    }
    __syncthreads();
    for (int i = threadIdx.x; i < nbuk; i += 256)
        if (h[i]) atomicAdd(&bcnt[i], h[i]);
}

// ---------------- bucket scan: exclusive scan of bcnt -> bbase, init bcur ----------------

__global__ __launch_bounds__(512) void bucket_scan_kernel(const unsigned* __restrict__ bcnt,
                                                          unsigned* __restrict__ bbase,
                                                          unsigned* __restrict__ bcur, int nbuk) {
    __shared__ unsigned tmp[512];
    __shared__ unsigned carry;
    if (threadIdx.x == 0) carry = 0u;
    __syncthreads();
    for (int base = 0; base < nbuk; base += 512) {
        int i = base + threadIdx.x;
        unsigned v = (i < nbuk) ? bcnt[i] : 0u;
        tmp[threadIdx.x] = v;
        __syncthreads();
#pragma unroll
        for (int off = 1; off < 512; off <<= 1) {
            unsigned t = (threadIdx.x >= (unsigned)off) ? tmp[threadIdx.x - off] : 0u;
            __syncthreads();
            tmp[threadIdx.x] += t;
            __syncthreads();
        }
        unsigned excl = tmp[threadIdx.x] - v + carry;
        if (i < nbuk) {
            bbase[i] = excl;
            bcur[(size_t)i * 16] = excl;   // line-strided cursor (one 64B line per bucket)
        }
        __syncthreads();
        if (threadIdx.x == 511) carry += tmp[511];
        __syncthreads();
    }
}

// ---------------- fill buckets: XCC-owned ranges + BLOCK-AGGREGATED cursor atomics ----------------
// (r3-proven) one cursor atomic per bucket per 16K chunk; LDS staging; contiguous runs.

__global__ __launch_bounds__(256) void fill_buckets_kernel(const int* __restrict__ ei,
                                                           const int* __restrict__ flag,
                                                           unsigned* __restrict__ bcur,
                                                           unsigned* __restrict__ ctr,
                                                           unsigned* __restrict__ tmpbuf,
                                                           int E, int nbuk) {
    int r = get_xcc();
    int bpx = (nbuk + 7) >> 3;
    int blo = r * bpx;
    int bhi = min(nbuk, blo + bpx);
    int nlb = bhi - blo;                 // <= 196
    bool is64 = (flag[0] != 0);
    const size_t dstoff = (size_t)2 * E;

    __shared__ unsigned stage[STAGE_CAP];
    __shared__ unsigned hist[256], lbase[256], lcur[256];
    __shared__ unsigned tail_s, chunk_s;

    int lane = threadIdx.x & 63;
    unsigned long long lmask_lt = (lane == 0) ? 0ull : ((~0ull) >> (64 - lane));

    auto stage_edge = [&](bool own, unsigned v, unsigned lb) {
        unsigned long long mask = __ballot(own ? 1 : 0);
        int cnt = __popcll(mask);
        if (cnt) {
            unsigned bp = 0;
            int leader = __builtin_ctzll(mask);
            if (lane == leader) bp = atomicAdd(&tail_s, (unsigned)cnt);
            bp = __shfl(bp, leader);
            if (own) {
                unsigned pos = bp + (unsigned)__popcll(mask & lmask_lt);
                if (pos < STAGE_CAP) {
                    stage[pos] = v;
                    atomicAdd(&hist[lb], 1u);
                } else {   // overflow: correct under any distribution
                    unsigned slot = __hip_atomic_fetch_add(&bcur[(size_t)(blo + (int)lb) * 16], 1u,
                                                           __ATOMIC_RELAXED, __HIP_MEMORY_SCOPE_WORKGROUP);
                    tmpbuf[slot] = v & 0x7fffffu;
                }
            }
        }
    };

    for (;;) {
        if (threadIdx.x == 0) {
            chunk_s = __hip_atomic_fetch_add(&ctr[r * 64], 1u, __ATOMIC_RELAXED,
                                             __HIP_MEMORY_SCOPE_WORKGROUP);
            tail_s = 0u;
        }
        if (threadIdx.x < 256) { hist[threadIdx.x] = 0u; lcur[threadIdx.x] = 0u; }
        __syncthreads();
        long long base = (long long)chunk_s * CHUNK_EDGES;
        if (base >= E) break;
        int end = (int)min((long long)E, base + CHUNK_EDGES);

        if (is64) {
            for (int e = (int)base + 2 * threadIdx.x; e + 1 < end; e += 512) {
                uint4 sv = *(const uint4*)(ei + (size_t)2 * e);
                uint4 dv = *(const uint4*)(ei + dstoff + (size_t)2 * e);
                {
                    int d = (int)dv.x;
                    int b = d >> B_BITS;
                    bool own = (b >= blo && b < bhi);
                    unsigned lb = own ? (unsigned)(b - blo) : 0u;
                    unsigned v = (lb << 23) | ((unsigned)(d & ((1 << B_BITS) - 1)) << SRC_BITS) | sv.x;
                    stage_edge(own, v, lb);
                }
                {
                    int d = (int)dv.z;
                    int b = d >> B_BITS;
                    bool own = (b >= blo && b < bhi);
                    unsigned lb = own ? (unsigned)(b - blo) : 0u;
                    unsigned v = (lb << 23) | ((unsigned)(d & ((1 << B_BITS) - 1)) << SRC_BITS) | sv.z;
                    stage_edge(own, v, lb);
                }
            }
            if ((end - (int)base) & 1) {
                bool own = false; unsigned v = 0, lb = 0;
                if (threadIdx.x == 0) {
                    int e = end - 1;
                    int d = ei[dstoff + (size_t)2 * e];
                    int b = d >> B_BITS;
                    if (b >= blo && b < bhi) {
                        own = true; lb = (unsigned)(b - blo);
                        v = (lb << 23) | ((unsigned)(d & ((1 << B_BITS) - 1)) << SRC_BITS)
                            | (unsigned)ei[(size_t)2 * e];
                    }
                }
                stage_edge(own, v, lb);
            }
        } else {
            for (int e = (int)base + threadIdx.x; e < end; e += 256) {
                int d = ei[(size_t)E + e];
                int b = d >> B_BITS;
                bool own = (b >= blo && b < bhi);
                unsigned lb = own ? (unsigned)(b - blo) : 0u;
                unsigned v = (lb << 23) | ((unsigned)(d & ((1 << B_BITS) - 1)) << SRC_BITS)
                             | (own ? (unsigned)ei[e] : 0u);
                stage_edge(own, v, lb);
            }
        }
        __syncthreads();

        for (int lb = threadIdx.x; lb < nlb; lb += 256) {
            unsigned h = hist[lb];
            if (h) lbase[lb] = __hip_atomic_fetch_add(&bcur[(size_t)(blo + lb) * 16], h,
                                                      __ATOMIC_RELAXED, __HIP_MEMORY_SCOPE_WORKGROUP);
        }
        __syncthreads();

        unsigned tl = min(tail_s, (unsigned)STAGE_CAP);
        for (unsigned i = threadIdx.x; i < tl; i += 256) {
            unsigned v = stage[i];
            unsigned lb = v >> 23;
            unsigned off = atomicAdd(&lcur[lb], 1u);
            tmpbuf[lbase[lb] + off] = v & 0x7fffffu;
        }
        __syncthreads();
    }
}

// ---------------- stage2: bucket -> exact CSR + deg + rowptr + dinv ----------------

__global__ __launch_bounds__(256) void bucket_to_csr_kernel(const unsigned* __restrict__ tmpbuf,
                                                            const unsigned* __restrict__ bbase,
                                                            unsigned* __restrict__ deg,
                                                            unsigned* __restrict__ rowptr,
                                                            float* __restrict__ dinv,
                                                            int* __restrict__ csr_src,
                                                            int nbuk, int N, int E) {
    int b = blockIdx.x;
    int tid = threadIdx.x;
    unsigned beg = bbase[b];
    unsigned end = (b + 1 < nbuk) ? bbase[b + 1] : (unsigned)E;
    int d0 = b << B_BITS;
    const int ND = 1 << B_BITS;
    __shared__ unsigned hist[ND], scn[ND], cur[ND];
    if (tid < ND) { hist[tid] = 0u; cur[tid] = 0u; }
    __syncthreads();
    for (unsigned i = beg + tid; i < end; i += 256)
        atomicAdd(&hist[tmpbuf[i] >> SRC_BITS], 1u);
    __syncthreads();
    if (tid == 0) {
        unsigned run = 0;
        for (int k = 0; k < ND; ++k) { scn[k] = run; run += hist[k]; }
    }
    __syncthreads();
    if (tid < ND) {
        int d = d0 + tid;
        if (d < N) {
            unsigned dg = hist[tid];
            deg[d] = dg;
            dinv[d] = rsqrtf((float)(dg + 1u));
            rowptr[d] = beg + scn[tid];
        }
    }
    __syncthreads();
    for (unsigned i = beg + tid; i < end; i += 256) {
        unsigned v = tmpbuf[i];
        unsigned dl = v >> SRC_BITS;
        unsigned s = v & ((1u << SRC_BITS) - 1u);
        unsigned p = atomicAdd(&cur[dl], 1u);
        csr_src[beg + scn[dl] + p] = (int)s;
    }
}

// ---------------- GEMM1 (MFMA): x @ W1 -> h1s SHARDED [8][N][4 u32] ----------------
// shard s holds bf16 feature pairs 4s..4s+3 (feats 8s..8s+7); rows 16B, table/shard 1.6MB.

__global__ __launch_bounds__(256) void gemm1_mfma_kernel(const float* __restrict__ x,
                                                         const float* __restrict__ W1,
                                                         unsigned* __restrict__ h1s, int N) {
    int lane = threadIdx.x & 63;
    int quad = lane >> 4;
    int col  = lane & 15;

    Frag B[4][4];
#pragma unroll
    for (int c = 0; c < 4; ++c)
#pragma unroll
        for (int ks = 0; ks < 4; ++ks) {
            int n = c * 16 + col;
#pragma unroll
            for (int jj = 0; jj < 4; ++jj) {
                int k = ks * 32 + quad * 8 + 2 * jj;
                B[c][ks].u[jj] = pack_bf16(W1[k * HIDDEN + n], W1[(k + 1) * HIDDEN + n]);
            }
        }

    int wave_id = blockIdx.x * 4 + (threadIdx.x >> 6);
    int nwaves  = gridDim.x * 4;
    int ntiles  = (N + 15) >> 4;

    for (int rt = wave_id; rt < ntiles; rt += nwaves) {
        int rowA = rt * 16 + col;
        Frag A[4];
#pragma unroll
        for (int ks = 0; ks < 4; ++ks) {
            float4 a0 = make_float4(0.f, 0.f, 0.f, 0.f), a1 = a0;
            if (rowA < N) {
                const float4* ap = (const float4*)(x + (size_t)rowA * N_FEAT + ks * 32 + quad * 8);
                a0 = ap[0];
                a1 = ap[1];
            }
            A[ks].u[0] = pack_bf16(a0.x, a0.y);
            A[ks].u[1] = pack_bf16(a0.z, a0.w);
            A[ks].u[2] = pack_bf16(a1.x, a1.y);
            A[ks].u[3] = pack_bf16(a1.z, a1.w);
        }
        f32x4 acc[4] = {{0.f, 0.f, 0.f, 0.f}, {0.f, 0.f, 0.f, 0.f},
                        {0.f, 0.f, 0.f, 0.f}, {0.f, 0.f, 0.f, 0.f}};
#pragma unroll
        for (int ks = 0; ks < 4; ++ks)
#pragma unroll
            for (int c = 0; c < 4; ++c)
                acc[c] = __builtin_amdgcn_mfma_f32_16x16x32_bf16(A[ks].v, B[c][ks].v, acc[c], 0, 0, 0);

        int rowD = rt * 16 + quad * 4;
#pragma unroll
        for (int c = 0; c < 4; ++c)
#pragma unroll
            for (int r = 0; r < 4; ++r) {
                float v = acc[c][r];
                float nxt = __shfl_down(v, 1);
                int row = rowD + r;
                if (((lane & 1) == 0) && row < N) {
                    int pair = (c * 16 + col) >> 1;
                    int shard = pair >> 2, slot = pair & 3;
                    h1s[(size_t)shard * N * 4 + (size_t)row * 4 + slot] = pack_bf16(v, nxt);
                }
            }
    }
}

// ---------------- sharded aggregation: XCD r handles shard r for ALL dst nodes ----------------
// Gather table per XCD = 1.6MB (L2-resident; capacity fix for r7's 100% miss rate).
// Lane map: el = lane>>2 (16 parallel edges), slot = lane&3 (4 u32 = 8 feats).
// Work: 32 line-strided counters/XCD; counter k hands chunks k, k+32, ... (256 nodes each).

__global__ __launch_bounds__(256) void agg1s_kernel(const unsigned* __restrict__ h1s,
                                                    const int* __restrict__ csr_src,
                                                    const unsigned* __restrict__ rowptr,
                                                    const unsigned* __restrict__ deg,
                                                    const float* __restrict__ dinv,
                                                    const float* __restrict__ b1,
                                                    unsigned* __restrict__ acts,
                                                    unsigned* __restrict__ ctr2, int N) {
    int r = get_xcc();
    const unsigned* tab = h1s + (size_t)r * N * 4;
    unsigned* otab = acts + (size_t)r * N * 4;
    int lane = threadIdx.x & 63;
    int wave = threadIdx.x >> 6;
    int el = lane >> 2, slot = lane & 3;
    float2 bb = ((const float2*)b1)[r * 4 + slot];
    int nchunks = (N + 255) >> 8;
    __shared__ unsigned chunk_s;
    int k0 = (blockIdx.x >> 3) & 31;
    for (int pass = 0; pass < 32; ++pass) {
        int k = (k0 + pass) & 31;
        unsigned* cp = &ctr2[(size_t)(r * 32 + k) * 16];
        for (;;) {
            if (threadIdx.x == 0) chunk_s = atomicAdd(cp, 1u);
            __syncthreads();
            unsigned idx = chunk_s;
            __syncthreads();
            unsigned chunk = (unsigned)k + 32u * idx;
            if (chunk >= (unsigned)nchunks) break;
            int d0 = (int)chunk * 256 + wave * 64;
            int d1 = min(N, d0 + 64);
            for (int d = d0; d < d1; ++d) {
                unsigned beg = rowptr[d];
                int len = (int)deg[d];
                float dv = dinv[d];
                float acc0 = 0.f, acc1 = 0.f;
                if (el == 0) {
                    float2 sv = unpack_bf16(tab[(size_t)d * 4 + slot]);
                    acc0 = dv * sv.x; acc1 = dv * sv.y;
                }
                for (int i = el; i < len; i += 16) {
                    int s = csr_src[beg + i];
                    float w = dinv[s];
                    float2 a = unpack_bf16(tab[(size_t)s * 4 + slot]);
                    acc0 += w * a.x; acc1 += w * a.y;
                }
                acc0 += __shfl_xor(acc0, 4);  acc1 += __shfl_xor(acc1, 4);
                acc0 += __shfl_xor(acc0, 8);  acc1 += __shfl_xor(acc1, 8);
                acc0 += __shfl_xor(acc0, 16); acc1 += __shfl_xor(acc1, 16);
                acc0 += __shfl_xor(acc0, 32); acc1 += __shfl_xor(acc1, 32);
                if (el == 0) {
                    float r0 = fmaxf(acc0 * dv + bb.x, 0.f);
                    float r1 = fmaxf(acc1 * dv + bb.y, 0.f);
                    otab[(size_t)d * 4 + slot] = pack_bf16(r0, r1);
                }
            }
        }
    }
}

// same structure, no bias/relu: g = A_hat @ act (algebra swap; W2 applied afterwards)

__global__ __launch_bounds__(256) void agg2s_kernel(const unsigned* __restrict__ acts,
                                                    const int* __restrict__ csr_src,
                                                    const unsigned* __restrict__ rowptr,
                                                    const unsigned* __restrict__ deg,
                                                    const float* __restrict__ dinv,
                                                    unsigned* __restrict__ gbs,
                                                    unsigned* __restrict__ ctr2, int N) {
    int r = get_xcc();
    const unsigned* tab = acts + (size_t)r * N * 4;
    unsigned* otab = gbs + (size_t)r * N * 4;
    int lane = threadIdx.x & 63;
    int wave = threadIdx.x >> 6;
    int el = lane >> 2, slot = lane & 3;
    int nchunks = (N + 255) >> 8;
    __shared__ unsigned chunk_s;
    int k0 = (blockIdx.x >> 3) & 31;
    for (int pass = 0; pass < 32; ++pass) {
        int k = (k0 + pass) & 31;
        unsigned* cp = &ctr2[(size_t)(r * 32 + k) * 16];
        for (;;) {
            if (threadIdx.x == 0) chunk_s = atomicAdd(cp, 1u);
            __syncthreads();
            unsigned idx = chunk_s;
            __syncthreads();
            unsigned chunk = (unsigned)k + 32u * idx;
            if (chunk >= (unsigned)nchunks) break;
            int d0 = (int)chunk * 256 + wave * 64;
            int d1 = min(N, d0 + 64);
            for (int d = d0; d < d1; ++d) {
                unsigned beg = rowptr[d];
                int len = (int)deg[d];
                float dv = dinv[d];
                float acc0 = 0.f, acc1 = 0.f;
                if (el == 0) {
                    float2 sv = unpack_bf16(tab[(size_t)d * 4 + slot]);
                    acc0 = dv * sv.x; acc1 = dv * sv.y;
                }
                for (int i = el; i < len; i += 16) {
                    int s = csr_src[beg + i];
                    float w = dinv[s];
                    float2 a = unpack_bf16(tab[(size_t)s * 4 + slot]);
                    acc0 += w * a.x; acc1 += w * a.y;
                }
                acc0 += __shfl_xor(acc0, 4);  acc1 += __shfl_xor(acc1, 4);
                acc0 += __shfl_xor(acc0, 8);  acc1 += __shfl_xor(acc1, 8);
                acc0 += __shfl_xor(acc0, 16); acc1 += __shfl_xor(acc1, 16);
                acc0 += __shfl_xor(acc0, 32); acc1 += __shfl_xor(acc1, 32);
                if (el == 0)
                    otab[(size_t)d * 4 + slot] = pack_bf16(acc0 * dv, acc1 * dv);
            }
        }
    }
}

// ---------------- fused GEMM2 + bias + log_softmax: one thread per node ----------------
// Collects the 8 gbs shards (coalesced 16B streams), z = g@W2 + b2 fully unrolled
// (compile-time W2 offsets -> scalar loads), LSM in-registers. (r5-proven cheap.)

__global__ __launch_bounds__(256) void gemm2lsm_kernel(const unsigned* __restrict__ gbs,
                                                       const float* __restrict__ W2,
                                                       const float* __restrict__ b2,
                                                       float* __restrict__ out, int N) {
    int d = blockIdx.x * 256 + threadIdx.x;
    if (d >= N) return;
    float z[N_CLS];
#pragma unroll
    for (int c = 0; c < N_CLS; ++c) z[c] = b2[c];

#pragma unroll
    for (int s = 0; s < 8; ++s) {
        uint4 u = *(const uint4*)(gbs + (size_t)s * N * 4 + (size_t)d * 4);
        float2 f0 = unpack_bf16(u.x), f1 = unpack_bf16(u.y);
        float2 f2 = unpack_bf16(u.z), f3 = unpack_bf16(u.w);
        float f[8] = {f0.x, f0.y, f1.x, f1.y, f2.x, f2.y, f3.x, f3.y};
#pragma unroll
        for (int q = 0; q < 8; ++q) {
            int k = s * 8 + q;
#pragma unroll
            for (int c = 0; c < N_CLS; ++c)
                z[c] = fmaf(f[q], W2[k * N_CLS + c], z[c]);
        }
    }
    float m = z[0];
#pragma unroll
    for (int c = 1; c < N_CLS; ++c) m = fmaxf(m, z[c]);
    float s = 0.f;
#pragma unroll
    for (int c = 0; c < N_CLS; ++c) s += __expf(z[c] - m);
    float ls = __logf(s) + m;
    float4* orow = (float4*)(out + (size_t)d * N_CLS);
#pragma unroll
    for (int q = 0; q < 10; ++q) {
        float4 o;
        o.x = z[q * 4 + 0] - ls; o.y = z[q * 4 + 1] - ls;
        o.z = z[q * 4 + 2] - ls; o.w = z[q * 4 + 3] - ls;
        orow[q] = o;
    }
}

// ---------------- launch ----------------

static inline size_t align_up(size_t x) { return (x + 255) & ~(size_t)255; }

extern "C" void kernel_launch(void* const* d_in, const int* in_sizes, int n_in,
                              void* d_out, int out_size, void* d_ws, size_t ws_size,
                              hipStream_t stream) {
    const float* x  = (const float*)d_in[0];
    const int*   ei = (const int*)d_in[1];
    const float* W1 = (const float*)d_in[2];
    const float* b1 = (const float*)d_in[3];
    const float* W2 = (const float*)d_in[4];
    const float* b2 = (const float*)d_in[5];

    int N = in_sizes[0] / N_FEAT;     // 100000
    int E = in_sizes[1] / 2;          // 1600000
    int nbuk = (N + (1 << B_BITS) - 1) >> B_BITS;   // 1563
    int nblk = (N + 255) / 256;

    char* ws = (char*)d_ws;
    int*      flag    = (int*)ws;       ws += 256;
    unsigned* ctrs    = (unsigned*)ws;  ws += 4096;                        // 8 XCD chunk counters (fill)
    unsigned* ctr2a   = (unsigned*)ws;  ws += 32768;                       // 8 XCD x 32 counters (agg1)
    unsigned* ctr2b   = (unsigned*)ws;  ws += 32768;                       // 8 XCD x 32 counters (agg2)
    unsigned* bcnt    = (unsigned*)ws;  ws += align_up((size_t)nbuk * 4);
    unsigned* bbase   = (unsigned*)ws;  ws += align_up((size_t)nbuk * 4);
    unsigned* bcur    = (unsigned*)ws;  ws += align_up((size_t)nbuk * 64); // line-strided cursors
    unsigned* deg     = (unsigned*)ws;  ws += align_up((size_t)N * 4);
    float*    dinv    = (float*)ws;     ws += align_up((size_t)N * 4);
    unsigned* rowptr  = (unsigned*)ws;  ws += align_up((size_t)N * 4);
    unsigned* tmpbuf  = (unsigned*)ws;  ws += align_up((size_t)E * 4);
    int*      csr_src = (int*)ws;       ws += align_up((size_t)E * 4);
    unsigned* h1s     = (unsigned*)ws;  ws += align_up((size_t)N * 32 * 4); // sharded bf16 [8][N][4u32]
    unsigned* acts    = (unsigned*)ws;  ws += align_up((size_t)N * 32 * 4); // sharded bf16
    unsigned* gbs     = (unsigned*)ws;  ws += align_up((size_t)N * 32 * 4); // sharded bf16

    hipMemsetAsync(ctrs, 0, 4096 + 32768 + 32768, stream);   // ctrs + ctr2a + ctr2b contiguous
    hipMemsetAsync(bcnt, 0, (size_t)nbuk * 4, stream);

    detect_layout_kernel<<<1, 64, 0, stream>>>(ei, flag);
    bucket_hist_kernel<<<256, 256, 0, stream>>>(ei, flag, bcnt, E, nbuk);
    bucket_scan_kernel<<<1, 512, 0, stream>>>(bcnt, bbase, bcur, nbuk);
    fill_buckets_kernel<<<FILL_BLOCKS, 256, 0, stream>>>(ei, flag, bcur, ctrs, tmpbuf, E, nbuk);
    bucket_to_csr_kernel<<<nbuk, 256, 0, stream>>>(tmpbuf, bbase, deg, rowptr, dinv, csr_src, nbuk, N, E);

    // layer 1
    gemm1_mfma_kernel<<<512, 256, 0, stream>>>(x, W1, h1s, N);
    agg1s_kernel<<<AGG_BLOCKS, 256, 0, stream>>>(h1s, csr_src, rowptr, deg, dinv, b1, acts, ctr2a, N);

    // layer 2 (algebra-swapped, sharded): g = A_hat @ act, then fused GEMM2+LSM
    agg2s_kernel<<<AGG_BLOCKS, 256, 0, stream>>>(acts, csr_src, rowptr, deg, dinv, gbs, ctr2b, N);
    gemm2lsm_kernel<<<nblk, 256, 0, stream>>>(gbs, W2, b2, (float*)d_out, N);
}

// Round 9
// 310.754 us; speedup vs baseline: 2.5082x; 2.5082x over previous
//
#include <hip/hip_runtime.h>
#include <hip/hip_bf16.h>
#include <string.h>

#define N_FEAT 128
#define HIDDEN 64
#define N_CLS  40
#define FILL_BLOCKS 2048
#define CHUNK_EDGES 16384        // big chunks -> one cursor atomic per bucket per chunk
#define STAGE_CAP 4096           // LDS 16KB -> 8 blocks/CU (expected ~2048 owned/chunk)
#define B_BITS 6                 // 64 dsts per bucket
#define SRC_BITS 17              // N <= 131072

typedef __bf16 bf16x8 __attribute__((ext_vector_type(8)));
typedef float  f32x4  __attribute__((ext_vector_type(4)));

union Frag { unsigned u[4]; bf16x8 v; };

// physical XCD id of the CU running this wave [measured: learn_hip m09]
static __device__ inline int get_xcc() {
    return (int)(__builtin_amdgcn_s_getreg((3 << 11) | 20) & 7u);
}

// ---------------- bf16 pack/unpack (manual, RNE) ----------------

static __device__ inline unsigned pack_bf16(float a, float b) {
    unsigned ba = __float_as_uint(a);
    unsigned bb = __float_as_uint(b);
    unsigned ra = (ba + 0x7fffu + ((ba >> 16) & 1u)) >> 16;
    unsigned rb = (bb + 0x7fffu + ((bb >> 16) & 1u)) >> 16;
    return (ra & 0xffffu) | (rb << 16);
}

static __device__ inline float2 unpack_bf16(unsigned v) {
    return make_float2(__uint_as_float(v << 16), __uint_as_float(v & 0xffff0000u));
}

// ---------------- edge layout detection ----------------

__global__ void detect_layout_kernel(const int* __restrict__ ei, int* __restrict__ flag) {
    int lane = threadIdx.x;                 // one wave
    int v = ei[2 * lane + 1];
    unsigned long long b = __ballot(v != 0);
    if (lane == 0) flag[0] = (b == 0ull) ? 1 : 0;   // 1 => int64 layout
}

// ---------------- bucket histogram: LDS hist per block, 8-way-split flush ----------------
// r8 lesson (rule #6): flushing 256 blocks into one bcnt copy = 256 serialized
// same-address RMWs (~21us). 8 copies -> 32/address (~3us). Scan sums the copies.

__global__ __launch_bounds__(256) void bucket_hist_kernel(const int* __restrict__ ei,
                                                          const int* __restrict__ flag,
                                                          unsigned* __restrict__ bcnt8,
                                                          int E, int nbuk) {
    __shared__ unsigned h[2048];
    for (int i = threadIdx.x; i < nbuk; i += 256) h[i] = 0u;
    __syncthreads();
    bool is64 = (flag[0] != 0);
    if (is64) {
        int idx = blockIdx.x * 256 + threadIdx.x;
        int stride2 = gridDim.x * 256 * 2;
        int Eeven = E & ~1;
        for (int e = idx * 2; e < Eeven; e += stride2) {
            uint4 dv = *(const uint4*)(ei + (size_t)2 * E + (size_t)2 * e);
            atomicAdd(&h[((int)dv.x) >> B_BITS], 1u);
            atomicAdd(&h[((int)dv.z) >> B_BITS], 1u);
        }
        for (int e = Eeven + idx; e < E; e += gridDim.x * 256) {
            int d = ei[(size_t)2 * E + (size_t)2 * e];
            atomicAdd(&h[d >> B_BITS], 1u);
        }
    } else {
        const int* dstp = ei + E;
        for (int e = blockIdx.x * 256 + threadIdx.x; e < E; e += gridDim.x * 256) {
            int d = dstp[e];
            atomicAdd(&h[d >> B_BITS], 1u);
        }
    }
    __syncthreads();
    unsigned copy = (blockIdx.x & 7u) << 11;   // 8 copies, 2048 apart
    for (int i = threadIdx.x; i < nbuk; i += 256)
        if (h[i]) atomicAdd(&bcnt8[copy + i], h[i]);
}

// ---------------- bucket scan: sum 8 copies, exclusive scan -> bbase, init bcur ----------------

__global__ __launch_bounds__(512) void bucket_scan_kernel(const unsigned* __restrict__ bcnt8,
                                                          unsigned* __restrict__ bbase,
                                                          unsigned* __restrict__ bcur, int nbuk) {
    __shared__ unsigned tmp[512];
    __shared__ unsigned carry;
    if (threadIdx.x == 0) carry = 0u;
    __syncthreads();
    for (int base = 0; base < nbuk; base += 512) {
        int i = base + threadIdx.x;
        unsigned v = 0u;
        if (i < nbuk) {
#pragma unroll
            for (int c = 0; c < 8; ++c) v += bcnt8[(c << 11) + i];
        }
        tmp[threadIdx.x] = v;
        __syncthreads();
#pragma unroll
        for (int off = 1; off < 512; off <<= 1) {
            unsigned t = (threadIdx.x >= (unsigned)off) ? tmp[threadIdx.x - off] : 0u;
            __syncthreads();
            tmp[threadIdx.x] += t;
            __syncthreads();
        }
        unsigned excl = tmp[threadIdx.x] - v + carry;
        if (i < nbuk) {
            bbase[i] = excl;
            bcur[(size_t)i * 16] = excl;   // line-strided cursor (one 64B line per bucket)
        }
        __syncthreads();
        if (threadIdx.x == 511) carry += tmp[511];
        __syncthreads();
    }
}

// ---------------- fill buckets: XCC-owned ranges + BLOCK-AGGREGATED cursor atomics ----------------
// (r3-proven) one cursor atomic per bucket per 16K chunk; LDS staging; contiguous runs.

__global__ __launch_bounds__(256) void fill_buckets_kernel(const int* __restrict__ ei,
                                                           const int* __restrict__ flag,
                                                           unsigned* __restrict__ bcur,
                                                           unsigned* __restrict__ ctr,
                                                           unsigned* __restrict__ tmpbuf,
                                                           int E, int nbuk) {
    int r = get_xcc();
    int bpx = (nbuk + 7) >> 3;
    int blo = r * bpx;
    int bhi = min(nbuk, blo + bpx);
    int nlb = bhi - blo;                 // <= 196
    bool is64 = (flag[0] != 0);
    const size_t dstoff = (size_t)2 * E;

    __shared__ unsigned stage[STAGE_CAP];
    __shared__ unsigned hist[256], lbase[256], lcur[256];
    __shared__ unsigned tail_s, chunk_s;

    int lane = threadIdx.x & 63;
    unsigned long long lmask_lt = (lane == 0) ? 0ull : ((~0ull) >> (64 - lane));

    auto stage_edge = [&](bool own, unsigned v, unsigned lb) {
        unsigned long long mask = __ballot(own ? 1 : 0);
        int cnt = __popcll(mask);
        if (cnt) {
            unsigned bp = 0;
            int leader = __builtin_ctzll(mask);
            if (lane == leader) bp = atomicAdd(&tail_s, (unsigned)cnt);
            bp = __shfl(bp, leader);
            if (own) {
                unsigned pos = bp + (unsigned)__popcll(mask & lmask_lt);
                if (pos < STAGE_CAP) {
                    stage[pos] = v;
                    atomicAdd(&hist[lb], 1u);
                } else {   // overflow: correct under any distribution
                    unsigned slot = __hip_atomic_fetch_add(&bcur[(size_t)(blo + (int)lb) * 16], 1u,
                                                           __ATOMIC_RELAXED, __HIP_MEMORY_SCOPE_WORKGROUP);
                    tmpbuf[slot] = v & 0x7fffffu;
                }
            }
        }
    };

    for (;;) {
        if (threadIdx.x == 0) {
            chunk_s = __hip_atomic_fetch_add(&ctr[r * 64], 1u, __ATOMIC_RELAXED,
                                             __HIP_MEMORY_SCOPE_WORKGROUP);
            tail_s = 0u;
        }
        if (threadIdx.x < 256) { hist[threadIdx.x] = 0u; lcur[threadIdx.x] = 0u; }
        __syncthreads();
        long long base = (long long)chunk_s * CHUNK_EDGES;
        if (base >= E) break;
        int end = (int)min((long long)E, base + CHUNK_EDGES);

        if (is64) {
            for (int e = (int)base + 2 * threadIdx.x; e + 1 < end; e += 512) {
                uint4 sv = *(const uint4*)(ei + (size_t)2 * e);
                uint4 dv = *(const uint4*)(ei + dstoff + (size_t)2 * e);
                {
                    int d = (int)dv.x;
                    int b = d >> B_BITS;
                    bool own = (b >= blo && b < bhi);
                    unsigned lb = own ? (unsigned)(b - blo) : 0u;
                    unsigned v = (lb << 23) | ((unsigned)(d & ((1 << B_BITS) - 1)) << SRC_BITS) | sv.x;
                    stage_edge(own, v, lb);
                }
                {
                    int d = (int)dv.z;
                    int b = d >> B_BITS;
                    bool own = (b >= blo && b < bhi);
                    unsigned lb = own ? (unsigned)(b - blo) : 0u;
                    unsigned v = (lb << 23) | ((unsigned)(d & ((1 << B_BITS) - 1)) << SRC_BITS) | sv.z;
                    stage_edge(own, v, lb);
                }
            }
            if ((end - (int)base) & 1) {
                bool own = false; unsigned v = 0, lb = 0;
                if (threadIdx.x == 0) {
                    int e = end - 1;
                    int d = ei[dstoff + (size_t)2 * e];
                    int b = d >> B_BITS;
                    if (b >= blo && b < bhi) {
                        own = true; lb = (unsigned)(b - blo);
                        v = (lb << 23) | ((unsigned)(d & ((1 << B_BITS) - 1)) << SRC_BITS)
                            | (unsigned)ei[(size_t)2 * e];
                    }
                }
                stage_edge(own, v, lb);
            }
        } else {
            for (int e = (int)base + threadIdx.x; e < end; e += 256) {
                int d = ei[(size_t)E + e];
                int b = d >> B_BITS;
                bool own = (b >= blo && b < bhi);
                unsigned lb = own ? (unsigned)(b - blo) : 0u;
                unsigned v = (lb << 23) | ((unsigned)(d & ((1 << B_BITS) - 1)) << SRC_BITS)
                             | (own ? (unsigned)ei[e] : 0u);
                stage_edge(own, v, lb);
            }
        }
        __syncthreads();

        for (int lb = threadIdx.x; lb < nlb; lb += 256) {
            unsigned h = hist[lb];
            if (h) lbase[lb] = __hip_atomic_fetch_add(&bcur[(size_t)(blo + lb) * 16], h,
                                                      __ATOMIC_RELAXED, __HIP_MEMORY_SCOPE_WORKGROUP);
        }
        __syncthreads();

        unsigned tl = min(tail_s, (unsigned)STAGE_CAP);
        for (unsigned i = threadIdx.x; i < tl; i += 256) {
            unsigned v = stage[i];
            unsigned lb = v >> 23;
            unsigned off = atomicAdd(&lcur[lb], 1u);
            tmpbuf[lbase[lb] + off] = v & 0x7fffffu;
        }
        __syncthreads();
    }
}

// ---------------- stage2: bucket -> exact CSR + deg + rowptr + dinv ----------------

__global__ __launch_bounds__(256) void bucket_to_csr_kernel(const unsigned* __restrict__ tmpbuf,
                                                            const unsigned* __restrict__ bbase,
                                                            unsigned* __restrict__ deg,
                                                            unsigned* __restrict__ rowptr,
                                                            float* __restrict__ dinv,
                                                            int* __restrict__ csr_src,
                                                            int nbuk, int N, int E) {
    int b = blockIdx.x;
    int tid = threadIdx.x;
    unsigned beg = bbase[b];
    unsigned end = (b + 1 < nbuk) ? bbase[b + 1] : (unsigned)E;
    int d0 = b << B_BITS;
    const int ND = 1 << B_BITS;
    __shared__ unsigned hist[ND], scn[ND], cur[ND];
    if (tid < ND) { hist[tid] = 0u; cur[tid] = 0u; }
    __syncthreads();
    for (unsigned i = beg + tid; i < end; i += 256)
        atomicAdd(&hist[tmpbuf[i] >> SRC_BITS], 1u);
    __syncthreads();
    if (tid == 0) {
        unsigned run = 0;
        for (int k = 0; k < ND; ++k) { scn[k] = run; run += hist[k]; }
    }
    __syncthreads();
    if (tid < ND) {
        int d = d0 + tid;
        if (d < N) {
            unsigned dg = hist[tid];
            deg[d] = dg;
            dinv[d] = rsqrtf((float)(dg + 1u));
            rowptr[d] = beg + scn[tid];
        }
    }
    __syncthreads();
    for (unsigned i = beg + tid; i < end; i += 256) {
        unsigned v = tmpbuf[i];
        unsigned dl = v >> SRC_BITS;
        unsigned s = v & ((1u << SRC_BITS) - 1u);
        unsigned p = atomicAdd(&cur[dl], 1u);
        csr_src[beg + scn[dl] + p] = (int)s;
    }
}

// ---------------- GEMM1 (MFMA): x[N,128] f32 @ W1[128,64] f32 -> h1 bf16 [N,64] ----------------

__global__ __launch_bounds__(256) void gemm1_mfma_kernel(const float* __restrict__ x,
                                                         const float* __restrict__ W1,
                                                         unsigned* __restrict__ h1b, int N) {
    int lane = threadIdx.x & 63;
    int quad = lane >> 4;
    int col  = lane & 15;

    Frag B[4][4];
#pragma unroll
    for (int c = 0; c < 4; ++c)
#pragma unroll
        for (int ks = 0; ks < 4; ++ks) {
            int n = c * 16 + col;
#pragma unroll
            for (int jj = 0; jj < 4; ++jj) {
                int k = ks * 32 + quad * 8 + 2 * jj;
                B[c][ks].u[jj] = pack_bf16(W1[k * HIDDEN + n], W1[(k + 1) * HIDDEN + n]);
            }
        }

    int wave_id = blockIdx.x * 4 + (threadIdx.x >> 6);
    int nwaves  = gridDim.x * 4;
    int ntiles  = (N + 15) >> 4;

    for (int rt = wave_id; rt < ntiles; rt += nwaves) {
        int rowA = rt * 16 + col;
        Frag A[4];
#pragma unroll
        for (int ks = 0; ks < 4; ++ks) {
            float4 a0 = make_float4(0.f, 0.f, 0.f, 0.f), a1 = a0;
            if (rowA < N) {
                const float4* ap = (const float4*)(x + (size_t)rowA * N_FEAT + ks * 32 + quad * 8);
                a0 = ap[0];
                a1 = ap[1];
            }
            A[ks].u[0] = pack_bf16(a0.x, a0.y);
            A[ks].u[1] = pack_bf16(a0.z, a0.w);
            A[ks].u[2] = pack_bf16(a1.x, a1.y);
            A[ks].u[3] = pack_bf16(a1.z, a1.w);
        }
        f32x4 acc[4] = {{0.f, 0.f, 0.f, 0.f}, {0.f, 0.f, 0.f, 0.f},
                        {0.f, 0.f, 0.f, 0.f}, {0.f, 0.f, 0.f, 0.f}};
#pragma unroll
        for (int ks = 0; ks < 4; ++ks)
#pragma unroll
            for (int c = 0; c < 4; ++c)
                acc[c] = __builtin_amdgcn_mfma_f32_16x16x32_bf16(A[ks].v, B[c][ks].v, acc[c], 0, 0, 0);

        int rowD = rt * 16 + quad * 4;
#pragma unroll
        for (int c = 0; c < 4; ++c)
#pragma unroll
            for (int r = 0; r < 4; ++r) {
                float v = acc[c][r];
                float nxt = __shfl_down(v, 1);
                int row = rowD + r;
                if (((lane & 1) == 0) && row < N)
                    h1b[(size_t)row * 32 + ((c * 16 + col) >> 1)] = pack_bf16(v, nxt);
            }
    }
}

// ---------------- GEMM2 (MFMA): act bf16 [N,64] @ W2[64,40] -> SPLIT h2a[N,16u32]+h2c[N,4u32] ----------------

__global__ __launch_bounds__(256) void gemm2_mfma_kernel(const unsigned* __restrict__ actb,
                                                         const float* __restrict__ W2,
                                                         unsigned* __restrict__ h2a,
                                                         unsigned* __restrict__ h2c, int N) {
    int lane = threadIdx.x & 63;
    int quad = lane >> 4;
    int col  = lane & 15;

    Frag B[3][2];
#pragma unroll
    for (int c = 0; c < 3; ++c)
#pragma unroll
        for (int ks = 0; ks < 2; ++ks) {
            int n = c * 16 + col;
#pragma unroll
            for (int jj = 0; jj < 4; ++jj) {
                int k = ks * 32 + quad * 8 + 2 * jj;
                float w0 = (n < N_CLS) ? W2[k * N_CLS + n] : 0.f;
                float w1 = (n < N_CLS) ? W2[(k + 1) * N_CLS + n] : 0.f;
                B[c][ks].u[jj] = pack_bf16(w0, w1);
            }
        }

    int wave_id = blockIdx.x * 4 + (threadIdx.x >> 6);
    int nwaves  = gridDim.x * 4;
    int ntiles  = (N + 15) >> 4;

    for (int rt = wave_id; rt < ntiles; rt += nwaves) {
        int rowA = rt * 16 + col;
        Frag A[2];
#pragma unroll
        for (int ks = 0; ks < 2; ++ks) {
            uint4 u = make_uint4(0u, 0u, 0u, 0u);
            if (rowA < N)
                u = *(const uint4*)(actb + (size_t)rowA * 32 + ks * 16 + quad * 4);
            A[ks].u[0] = u.x; A[ks].u[1] = u.y; A[ks].u[2] = u.z; A[ks].u[3] = u.w;
        }
        f32x4 acc[3] = {{0.f, 0.f, 0.f, 0.f}, {0.f, 0.f, 0.f, 0.f}, {0.f, 0.f, 0.f, 0.f}};
#pragma unroll
        for (int ks = 0; ks < 2; ++ks)
#pragma unroll
            for (int c = 0; c < 3; ++c)
                acc[c] = __builtin_amdgcn_mfma_f32_16x16x32_bf16(A[ks].v, B[c][ks].v, acc[c], 0, 0, 0);

        int rowD = rt * 16 + quad * 4;
#pragma unroll
        for (int c = 0; c < 3; ++c)
#pragma unroll
            for (int r = 0; r < 4; ++r) {
                float v = acc[c][r];
                float nxt = __shfl_down(v, 1);
                int row = rowD + r;
                int pair = (c * 16 + col) >> 1;
                if (((lane & 1) == 0) && row < N) {
                    if (pair < 16)
                        h2a[(size_t)row * 16 + pair] = pack_bf16(v, nxt);
                    else if (pair < 20)
                        h2c[(size_t)row * 4 + (pair - 16)] = pack_bf16(v, nxt);
                }
            }
    }
}

// ---------------- layer-1 agg: 16-edge unrolled CSR gather + self + bias + ReLU ----------------
// r8 rule #5: random gathers are txn-latency x concurrency bound -> 16 rows in flight/iter.

__global__ __launch_bounds__(256) void agg1_kernel(const unsigned* __restrict__ h1b,
                                                   const int* __restrict__ csr_src,
                                                   const unsigned* __restrict__ rowptr,
                                                   const unsigned* __restrict__ deg,
                                                   const float* __restrict__ dinv,
                                                   const float* __restrict__ b1,
                                                   unsigned* __restrict__ actb, int N) {
    int wave = threadIdx.x >> 6, lane = threadIdx.x & 63;
    int sub = lane >> 5, j = lane & 31;
    int d = blockIdx.x * 4 + wave;
    if (d >= N) return;
    float dv = dinv[d];
    float acc0 = 0.f, acc1 = 0.f;
    if (sub == 0) {
        float2 v = unpack_bf16(h1b[(size_t)d * 32 + j]);
        acc0 = dv * v.x; acc1 = dv * v.y;
    }
    unsigned beg = rowptr[d];
    int len = (int)deg[d];
    int i = 0;
    for (; i + 16 <= len; i += 16) {
        int s0 = csr_src[beg + i + sub];
        int s1 = csr_src[beg + i + 2 + sub];
        int s2 = csr_src[beg + i + 4 + sub];
        int s3 = csr_src[beg + i + 6 + sub];
        int s4 = csr_src[beg + i + 8 + sub];
        int s5 = csr_src[beg + i + 10 + sub];
        int s6 = csr_src[beg + i + 12 + sub];
        int s7 = csr_src[beg + i + 14 + sub];
        float w0 = dinv[s0], w1 = dinv[s1], w2 = dinv[s2], w3 = dinv[s3];
        float w4 = dinv[s4], w5 = dinv[s5], w6 = dinv[s6], w7 = dinv[s7];
        unsigned v0 = h1b[(size_t)s0 * 32 + j];
        unsigned v1 = h1b[(size_t)s1 * 32 + j];
        unsigned v2 = h1b[(size_t)s2 * 32 + j];
        unsigned v3 = h1b[(size_t)s3 * 32 + j];
        unsigned v4 = h1b[(size_t)s4 * 32 + j];
        unsigned v5 = h1b[(size_t)s5 * 32 + j];
        unsigned v6 = h1b[(size_t)s6 * 32 + j];
        unsigned v7 = h1b[(size_t)s7 * 32 + j];
        float2 a0 = unpack_bf16(v0), a1 = unpack_bf16(v1);
        float2 a2 = unpack_bf16(v2), a3 = unpack_bf16(v3);
        float2 a4 = unpack_bf16(v4), a5 = unpack_bf16(v5);
        float2 a6 = unpack_bf16(v6), a7 = unpack_bf16(v7);
        acc0 += w0 * a0.x + w1 * a1.x + w2 * a2.x + w3 * a3.x
              + w4 * a4.x + w5 * a5.x + w6 * a6.x + w7 * a7.x;
        acc1 += w0 * a0.y + w1 * a1.y + w2 * a2.y + w3 * a3.y
              + w4 * a4.y + w5 * a5.y + w6 * a6.y + w7 * a7.y;
    }
    for (; i + 8 <= len; i += 8) {
        int s0 = csr_src[beg + i + sub];
        int s1 = csr_src[beg + i + 2 + sub];
        int s2 = csr_src[beg + i + 4 + sub];
        int s3 = csr_src[beg + i + 6 + sub];
        float w0 = dinv[s0], w1 = dinv[s1], w2 = dinv[s2], w3 = dinv[s3];
        unsigned v0 = h1b[(size_t)s0 * 32 + j];
        unsigned v1 = h1b[(size_t)s1 * 32 + j];
        unsigned v2 = h1b[(size_t)s2 * 32 + j];
        unsigned v3 = h1b[(size_t)s3 * 32 + j];
        float2 a0 = unpack_bf16(v0), a1 = unpack_bf16(v1);
        float2 a2 = unpack_bf16(v2), a3 = unpack_bf16(v3);
        acc0 += w0 * a0.x + w1 * a1.x + w2 * a2.x + w3 * a3.x;
        acc1 += w0 * a0.y + w1 * a1.y + w2 * a2.y + w3 * a3.y;
    }
    for (; i + 4 <= len; i += 4) {
        int sA = csr_src[beg + i + sub];
        int sB = csr_src[beg + i + 2 + sub];
        float wA = dinv[sA], wB = dinv[sB];
        float2 a = unpack_bf16(h1b[(size_t)sA * 32 + j]);
        float2 b = unpack_bf16(h1b[(size_t)sB * 32 + j]);
        acc0 += wA * a.x + wB * b.x;
        acc1 += wA * a.y + wB * b.y;
    }
    for (; i < len; i += 2) {
        int e = i + sub;
        if (e < len) {
            int s = csr_src[beg + e];
            float w = dinv[s];
            float2 a = unpack_bf16(h1b[(size_t)s * 32 + j]);
            acc0 += w * a.x;
            acc1 += w * a.y;
        }
    }
    acc0 += __shfl_xor(acc0, 32);
    acc1 += __shfl_xor(acc1, 32);
    if (sub == 0) {
        float2 bb = ((const float2*)b1)[j];
        float r0 = fmaxf(acc0 * dv + bb.x, 0.f);
        float r1 = fmaxf(acc1 * dv + bb.y, 0.f);
        actb[(size_t)d * 32 + j] = pack_bf16(r0, r1);
    }
}

// ---------------- layer-2 agg: split-table 16-edge gather + bias + log_softmax ----------------

__global__ __launch_bounds__(256) void agg2_lsm_kernel(const unsigned* __restrict__ h2a,
                                                       const unsigned* __restrict__ h2c,
                                                       const int* __restrict__ csr_src,
                                                       const unsigned* __restrict__ rowptr,
                                                       const unsigned* __restrict__ deg,
                                                       const float* __restrict__ dinv,
                                                       const float* __restrict__ b2,
                                                       float* __restrict__ out, int N) {
    int wave = threadIdx.x >> 6, lane = threadIdx.x & 63;
    int sub = lane >> 5, j = lane & 31;
    bool act = (j < 20);
    const unsigned* tab;
    unsigned str;
    if (j < 16) { tab = h2a + j; str = 16u; }
    else        { tab = h2c + (j - 16); str = 4u; }
    int d = blockIdx.x * 4 + wave;
    if (d >= N) return;
    float dv = dinv[d];
    float acc0 = 0.f, acc1 = 0.f;
    if (sub == 0 && act) {
        float2 v = unpack_bf16(tab[(size_t)d * str]);
        acc0 = dv * v.x; acc1 = dv * v.y;
    }
    unsigned beg = rowptr[d];
    int len = (int)deg[d];
    int i = 0;
    for (; i + 16 <= len; i += 16) {
        int s0 = csr_src[beg + i + sub];
        int s1 = csr_src[beg + i + 2 + sub];
        int s2 = csr_src[beg + i + 4 + sub];
        int s3 = csr_src[beg + i + 6 + sub];
        int s4 = csr_src[beg + i + 8 + sub];
        int s5 = csr_src[beg + i + 10 + sub];
        int s6 = csr_src[beg + i + 12 + sub];
        int s7 = csr_src[beg + i + 14 + sub];
        float w0 = dinv[s0], w1 = dinv[s1], w2 = dinv[s2], w3 = dinv[s3];
        float w4 = dinv[s4], w5 = dinv[s5], w6 = dinv[s6], w7 = dinv[s7];
        if (act) {
            float2 a0 = unpack_bf16(tab[(size_t)s0 * str]);
            float2 a1 = unpack_bf16(tab[(size_t)s1 * str]);
            float2 a2 = unpack_bf16(tab[(size_t)s2 * str]);
            float2 a3 = unpack_bf16(tab[(size_t)s3 * str]);
            float2 a4 = unpack_bf16(tab[(size_t)s4 * str]);
            float2 a5 = unpack_bf16(tab[(size_t)s5 * str]);
            float2 a6 = unpack_bf16(tab[(size_t)s6 * str]);
            float2 a7 = unpack_bf16(tab[(size_t)s7 * str]);
            acc0 += w0 * a0.x + w1 * a1.x + w2 * a2.x + w3 * a3.x
                  + w4 * a4.x + w5 * a5.x + w6 * a6.x + w7 * a7.x;
            acc1 += w0 * a0.y + w1 * a1.y + w2 * a2.y + w3 * a3.y
                  + w4 * a4.y + w5 * a5.y + w6 * a6.y + w7 * a7.y;
        }
    }
    for (; i + 8 <= len; i += 8) {
        int s0 = csr_src[beg + i + sub];
        int s1 = csr_src[beg + i + 2 + sub];
        int s2 = csr_src[beg + i + 4 + sub];
        int s3 = csr_src[beg + i + 6 + sub];
        float w0 = dinv[s0], w1 = dinv[s1], w2 = dinv[s2], w3 = dinv[s3];
        if (act) {
            float2 a0 = unpack_bf16(tab[(size_t)s0 * str]);
            float2 a1 = unpack_bf16(tab[(size_t)s1 * str]);
            float2 a2 = unpack_bf16(tab[(size_t)s2 * str]);
            float2 a3 = unpack_bf16(tab[(size_t)s3 * str]);
            acc0 += w0 * a0.x + w1 * a1.x + w2 * a2.x + w3 * a3.x;
            acc1 += w0 * a0.y + w1 * a1.y + w2 * a2.y + w3 * a3.y;
        }
    }
    for (; i + 4 <= len; i += 4) {
        int sA = csr_src[beg + i + sub];
        int sB = csr_src[beg + i + 2 + sub];
        float wA = dinv[sA], wB = dinv[sB];
        if (act) {
            float2 a = unpack_bf16(tab[(size_t)sA * str]);
            float2 b = unpack_bf16(tab[(size_t)sB * str]);
            acc0 += wA * a.x + wB * b.x;
            acc1 += wA * a.y + wB * b.y;
        }
    }
    for (; i < len; i += 2) {
        int e = i + sub;
        if (e < len && act) {
            int s = csr_src[beg + e];
            float w = dinv[s];
            float2 a = unpack_bf16(tab[(size_t)s * str]);
            acc0 += w * a.x;
            acc1 += w * a.y;
        }
    }
    acc0 += __shfl_xor(acc0, 32);
    acc1 += __shfl_xor(acc1, 32);
    float v0 = -1e30f, v1 = -1e30f;
    if (act) {
        float2 bb = ((const float2*)b2)[j];
        v0 = acc0 * dv + bb.x;
        v1 = acc1 * dv + bb.y;
    }
    float m = fmaxf(v0, v1);
#pragma unroll
    for (int off = 32; off > 0; off >>= 1)
        m = fmaxf(m, __shfl_xor(m, off));
    float ex = (act && sub == 0) ? (expf(v0 - m) + expf(v1 - m)) : 0.f;
#pragma unroll
    for (int off = 32; off > 0; off >>= 1)
        ex += __shfl_xor(ex, off);
    float ls = logf(ex);
    if (act && sub == 0) {
        float2* orow = (float2*)(out + (size_t)d * N_CLS);
        orow[j] = make_float2(v0 - m - ls, v1 - m - ls);
    }
}

// ---------------- launch ----------------

static inline size_t align_up(size_t x) { return (x + 255) & ~(size_t)255; }

extern "C" void kernel_launch(void* const* d_in, const int* in_sizes, int n_in,
                              void* d_out, int out_size, void* d_ws, size_t ws_size,
                              hipStream_t stream) {
    const float* x  = (const float*)d_in[0];
    const int*   ei = (const int*)d_in[1];
    const float* W1 = (const float*)d_in[2];
    const float* b1 = (const float*)d_in[3];
    const float* W2 = (const float*)d_in[4];
    const float* b2 = (const float*)d_in[5];

    int N = in_sizes[0] / N_FEAT;     // 100000
    int E = in_sizes[1] / 2;          // 1600000
    int nbuk = (N + (1 << B_BITS) - 1) >> B_BITS;   // 1563

    char* ws = (char*)d_ws;
    int*      flag    = (int*)ws;       ws += 256;
    unsigned* ctrs    = (unsigned*)ws;  ws += 4096;                        // 8 XCD chunk counters, 256B apart
    unsigned* bcnt8   = (unsigned*)ws;  ws += 8 * 2048 * 4;                // 8 histogram copies
    unsigned* bbase   = (unsigned*)ws;  ws += align_up((size_t)nbuk * 4);
    unsigned* bcur    = (unsigned*)ws;  ws += align_up((size_t)nbuk * 64); // line-strided cursors
    unsigned* deg     = (unsigned*)ws;  ws += align_up((size_t)N * 4);
    float*    dinv    = (float*)ws;     ws += align_up((size_t)N * 4);
    unsigned* rowptr  = (unsigned*)ws;  ws += align_up((size_t)N * 4);
    unsigned* tmpbuf  = (unsigned*)ws;  ws += align_up((size_t)E * 4);
    int*      csr_src = (int*)ws;       ws += align_up((size_t)E * 4);
    unsigned* h1b     = (unsigned*)ws;  ws += align_up((size_t)N * 32 * 4);   // bf16 [N,64]
    unsigned* actb    = (unsigned*)ws;  ws += align_up((size_t)N * 32 * 4);   // bf16 [N,64]
    unsigned* h2a     = (unsigned*)ws;  ws += align_up((size_t)N * 16 * 4);   // bf16 [N,32], 64B rows
    unsigned* h2c     = (unsigned*)ws;  ws += align_up((size_t)N * 4 * 4);    // bf16 [N,8], 16B rows

    hipMemsetAsync(ctrs, 0, 4096 + 8 * 2048 * 4, stream);   // ctrs + bcnt8 contiguous

    detect_layout_kernel<<<1, 64, 0, stream>>>(ei, flag);
    bucket_hist_kernel<<<256, 256, 0, stream>>>(ei, flag, bcnt8, E, nbuk);
    bucket_scan_kernel<<<1, 512, 0, stream>>>(bcnt8, bbase, bcur, nbuk);
    fill_buckets_kernel<<<FILL_BLOCKS, 256, 0, stream>>>(ei, flag, bcur, ctrs, tmpbuf, E, nbuk);
    bucket_to_csr_kernel<<<nbuk, 256, 0, stream>>>(tmpbuf, bbase, deg, rowptr, dinv, csr_src, nbuk, N, E);

    // layer 1
    gemm1_mfma_kernel<<<512, 256, 0, stream>>>(x, W1, h1b, N);
    agg1_kernel<<<(N + 3) / 4, 256, 0, stream>>>(h1b, csr_src, rowptr, deg, dinv, b1, actb, N);

    // layer 2
    gemm2_mfma_kernel<<<512, 256, 0, stream>>>(actb, W2, h2a, h2c, N);
    agg2_lsm_kernel<<<(N + 3) / 4, 256, 0, stream>>>(h2a, h2c, csr_src, rowptr, deg, dinv, b2, (float*)d_out, N);
}